// Round 16
// baseline (128.416 us; speedup 1.0000x reference)
//
#include <hip/hip_runtime.h>
#include <hip/hip_bf16.h>
#include <hip/hip_fp16.h>

#define NPTS 8192
#define NB 4
#define R2C 0.5625f
#define BSC (64.0f/0.5625f)
#define RPW 2      // rows per work unit
#define WPB 4      // waves per block
#define NGRP 256   // 32-pt groups per batch
#define NUNITS (NB*NPTS/RPW)   // 16384
#define GPB (NPTS/RPW)         // 4096 units per batch
#define NBLK 2048              // main_k grid
#define NCTR 64                // distributed steal counters
#define UPC (NUNITS/NCTR)      // 256 units per counter
#define CSTRIDE 32             // u32 stride between counters (128 B)
#define DONE_IDX (NCTR*CSTRIDE)  // done-counter slot (index 2048)

typedef unsigned char u8;
typedef unsigned u32;
typedef unsigned long long u64;

__device__ __forceinline__ float wsum(float v){
#pragma unroll
  for (int o=32;o>0;o>>=1) v += __shfl_xor(v,o,64);
  return v;
}
__device__ __forceinline__ float rfl(float v){
  return __int_as_float(__builtin_amdgcn_readfirstlane(__float_as_int(v)));
}
__device__ __forceinline__ int cellof(float x,float y,float z){
  int ix=min(15,max(0,(int)((x+5.f)*1.6f)));
  int iy=min(15,max(0,(int)((y+5.f)*1.6f)));
  int iz=min(15,max(0,(int)((z+5.f)*1.6f)));
  int sx=(ix&1)|((ix&2)<<2)|((ix&4)<<4)|((ix&8)<<6);
  int sy=(iy&1)|((iy&2)<<2)|((iy&4)<<4)|((iy&8)<<6);
  int sz=(iz&1)|((iz&2)<<2)|((iz&4)<<4)|((iz&8)<<6);
  return (sx<<2)|(sy<<1)|sz;
}
// orderable u32 <-> float (monotone), for atomicMin/Max-based AABB
__device__ __forceinline__ u32 om(float f){
  u32 u=__float_as_uint(f);
  return (u&0x80000000u)? ~u : (u|0x80000000u);
}
__device__ __forceinline__ float iom(u32 m){
  u32 u=(m&0x80000000u)? (m&0x7fffffffu) : ~m;
  return __uint_as_float(u);
}

// ---------------- fused sort pipeline (1024 threads/block, wave-parallel scan) ----
__global__ __launch_bounds__(1024) void sort_k(
    const float* __restrict__ pc, const float* __restrict__ fl,
    float4* __restrict__ pA, float2* __restrict__ pB,
    unsigned short* __restrict__ ab, u32* __restrict__ ctr){
  __shared__ u32 hist[4096];     // 16 KB
  __shared__ u32 amm[NGRP*6];    // 6 KB
  __shared__ u32 wsums[16];
  const int b=blockIdx.x, tid=threadIdx.x, lane=tid&63, wid=tid>>6;
  for (int i=tid;i<4096;i+=1024) hist[i]=0u;
  for (int i=tid;i<NGRP*6;i+=1024) amm[i]=(i&1)?0u:0xFFFFFFFFu;  // even=min,odd=max
  if (b==0) for (int i=tid;i<NCTR*CSTRIDE+32;i+=1024) ctr[i]=0u;
  __syncthreads();
  const float* pcb=pc+(size_t)b*NPTS*3;
  const float* flb=fl+(size_t)b*NPTS*3;
  for (int i=tid;i<NPTS;i+=1024){
    float x=pcb[3*i],y=pcb[3*i+1],z=pcb[3*i+2];
    atomicAdd(&hist[cellof(x,y,z)],1u);
  }
  __syncthreads();
  // hierarchical exclusive scan: 4 cells/thread -> wave scan -> wave-total prefix
  {
    u32 loc[4]; u32 run=0;
#pragma unroll
    for (int k=0;k<4;k++){ u32 v=hist[tid*4+k]; loc[k]=run; run+=v; }
    u32 inc=run;
#pragma unroll
    for (int o=1;o<64;o<<=1){ u32 y=__shfl_up(inc,o,64); if (lane>=o) inc+=y; }
    if (lane==63) wsums[wid]=inc;
    __syncthreads();
    u32 wbase=0;
    for (int i=0;i<wid;i++) wbase+=wsums[i];
    u32 tbase=wbase+inc-run;
#pragma unroll
    for (int k=0;k<4;k++) hist[tid*4+k]=tbase+loc[k];
  }
  __syncthreads();
  for (int i=tid;i<NPTS;i+=1024){
    float x=pcb[3*i],y=pcb[3*i+1],z=pcb[3*i+2];
    int c=cellof(x,y,z);
    u32 pos=atomicAdd(&hist[c],1u);
    int d=b*NPTS+(int)pos;
    pA[d]=make_float4(x,y,z,flb[3*i]);
    pB[d]=make_float2(flb[3*i+1],flb[3*i+2]);
    int g=(int)(pos>>5);
    atomicMin(&amm[g*6+0],om(x)); atomicMax(&amm[g*6+1],om(x));
    atomicMin(&amm[g*6+2],om(y)); atomicMax(&amm[g*6+3],om(y));
    atomicMin(&amm[g*6+4],om(z)); atomicMax(&amm[g*6+5],om(z));
  }
  __syncthreads();
  if (tid<NGRP){
    unsigned short* p6=ab+(b*NGRP+tid)*6;
    p6[0]=__half_as_ushort(__float2half_rd(iom(amm[tid*6+0])));
    p6[1]=__half_as_ushort(__float2half_ru(iom(amm[tid*6+1])));
    p6[2]=__half_as_ushort(__float2half_rd(iom(amm[tid*6+2])));
    p6[3]=__half_as_ushort(__float2half_ru(iom(amm[tid*6+3])));
    p6[4]=__half_as_ushort(__float2half_rd(iom(amm[tid*6+4])));
    p6[5]=__half_as_ushort(__float2half_ru(iom(amm[tid*6+5])));
  }
}

// ---------------- main loss kernel: single-pass, packed u64 hist, depth-2 prefetch,
// last-finishing block performs the final reduction (no separate finp_k launch).
__global__ __launch_bounds__(256,4) void main_k(
  const float* __restrict__ fl, const float* __restrict__ gt,
  const float4* __restrict__ gpA, const float2* __restrict__ gpB,
  const unsigned short* __restrict__ ab,
  float* __restrict__ part, u32* __restrict__ ctr, float* __restrict__ out)
{
  __shared__ unsigned short sab[NB][NGRP*6];   // 12 KB
  __shared__ u64  histp[WPB][RPW][64];         // 4 KB
  __shared__ u8   glg[WPB][NGRP];              // 1 KB
  __shared__ float wred[WPB][3];
  __shared__ int lastf;

  const int tid=threadIdx.x, lane=tid&63, wv=tid>>6, bid=blockIdx.x;
  const u64 lt=(1ull<<lane)-1ull;
  const bool lo=(lane<32);
  const int l5=lane&31;

  { const u32* s=(const u32*)ab;
    u32* d=(u32*)&sab[0][0];
    for (int k=tid;k<NB*NGRP*3;k+=256) d[k]=s[k]; }
  __syncthreads();

  // data loss (grid-stride)
  float dl=0.f;
  for (int e=bid*256+tid; e<NB*NPTS*3; e+=gridDim.x*256) dl+=fabsf(fl[e]-gt[e]);
  dl=wsum(dl);

  float tknn=0.f, tbq=0.f;
  int cp=bid&(NCTR-1);

  for (;;){
    int k;
    if (lane==0){
      u32 kk=atomicAdd(&ctr[cp*CSTRIDE],1u);
      if (kk>=UPC){
        kk=0x7fffffffu;
        int qb=cp&~3;
#pragma unroll
        for (int t=0;t<4;t++){
          int c2=qb+t;
          if (c2==cp) continue;
          u32 v=*(volatile u32*)&ctr[c2*CSTRIDE];
          if (v<UPC){
            u32 k2=atomicAdd(&ctr[c2*CSTRIDE],1u);
            if (k2<UPC){ cp=c2; kk=k2; break; }
          }
        }
      }
      k=(int)kk;
    }
    k=__shfl(k,0,64);
    cp=__shfl(cp,0,64);
    if (k>=UPC) break;
    const int u=cp+(k<<6);

    const int b=u>>12;
    const int i0=(u&(GPB-1))*RPW;
    const float4* pA=gpA+b*NPTS;
    const float2* pB=gpB+b*NPTS;

    float rx[RPW],ry[RPW],rz[RPW],rfx[RPW],rfy[RPW],rfz[RPW];
#pragma unroll
    for (int r=0;r<RPW;r++){
      float4 A=pA[i0+r]; float2 B=pB[i0+r];
      rx[r]=rfl(A.x); ry[r]=rfl(A.y); rz[r]=rfl(A.z);
      rfx[r]=rfl(A.w); rfy[r]=rfl(B.x); rfz[r]=rfl(B.y);
    }
    float wx0=rx[0],wx1=rx[0],wy0=ry[0],wy1=ry[0],wz0=rz[0],wz1=rz[0];
#pragma unroll
    for (int r=1;r<RPW;r++){
      wx0=fminf(wx0,rx[r]); wx1=fmaxf(wx1,rx[r]);
      wy0=fminf(wy0,ry[r]); wy1=fmaxf(wy1,ry[r]);
      wz0=fminf(wz0,rz[r]); wz1=fmaxf(wz1,rz[r]);
    }

    // classify 256 groups (lane handles h*64+lane) + ballot-compact ascending list
    int nsur;
    {
      int base=0;
#pragma unroll
      for (int h=0;h<4;h++){
        const unsigned short* a=&sab[b][(h*64+lane)*6];
        float gx0=__half2float(__ushort_as_half(a[0])), gx1=__half2float(__ushort_as_half(a[1]));
        float gy0=__half2float(__ushort_as_half(a[2])), gy1=__half2float(__ushort_as_half(a[3]));
        float gz0=__half2float(__ushort_as_half(a[4])), gz1=__half2float(__ushort_as_half(a[5]));
        float dxm=fmaxf(0.f,fmaxf(gx0-wx1,wx0-gx1));
        float dym=fmaxf(0.f,fmaxf(gy0-wy1,wy0-gy1));
        float dzm=fmaxf(0.f,fmaxf(gz0-wz1,wz0-gz1));
        float d2=fmaf(dxm,dxm,fmaf(dym,dym,dzm*dzm));
        bool c=d2<R2C;
        u64 bm=__ballot(c);
        if (c){ int p=base+__popcll(bm&lt); glg[wv][p]=(u8)(h*64+lane); }
        base+=__popcll(bm);
      }
      nsur=base;
    }
#pragma unroll
    for (int r=0;r<RPW;r++) histp[wv][r][lane]=0ull;

    // ---- single pass: packed count+L1 histogram + online ball query ----
    int cnt[RPW]; float f1[RPW]; float bqa=0.f;
#pragma unroll
    for (int r=0;r<RPW;r++){ cnt[r]=0; f1[r]=0.f; }
    {
      const int npair=(nsur+1)>>1;
      int s0=(0)|(lo?0:1);               // pair 0
      int jb=(int)glg[wv][min(s0,nsur-1)]*32+l5;
      float4 J=pA[jb]; float2 JF=pB[jb];
      int s1=(min(1,npair-1)<<1)|(lo?0:1);
      int jb1=(int)glg[wv][min(s1,nsur-1)]*32+l5;
      float4 N1=pA[jb1]; float2 NF1=pB[jb1];
#pragma unroll 1
      for (int t=0;t<npair;t++){
        int s2=(min(t+2,npair-1)<<1)|(lo?0:1);
        int jb2=(int)glg[wv][min(s2,nsur-1)]*32+l5;
        float4 N2=pA[jb2]; float2 NF2=pB[jb2];
        bool vld=lo||((t<<1)+1<nsur);
        bool open=false;
#pragma unroll
        for (int r=0;r<RPW;r++) open = open || (cnt[r]<64);
#pragma unroll
        for (int r=0;r<RPW;r++){
          float dx=rx[r]-J.x, dy=ry[r]-J.y, dz=rz[r]-J.z;
          float sq=fmaf(dx,dx,fmaf(dy,dy,dz*dz));
          bool in=(sq<R2C)&&vld;
          if (in){
            int bin=min((int)(sq*BSC),63);
            float l1=fabsf(J.w-rfx[r])+fabsf(JF.x-rfy[r])+fabsf(JF.y-rfz[r]);
            atomicAdd(&histp[wv][r][bin],(1ull<<44)+(u64)(l1*16777216.0f));
          }
          if (cnt[r]<64){
            u64 m=__ballot(in);
            if (in){
              int p=cnt[r]+__popcll(m&lt);
              if (p<64){
                float l1=fabsf(J.w-rfx[r])+fabsf(JF.x-rfy[r])+fabsf(JF.y-rfz[r]);
                bqa+=l1;
                if (p==0) f1[r]=l1;
              }
            }
            cnt[r]+=__popcll(m);
          }
        }
        J=N1; JF=NF1; N1=N2; NF1=NF2;
      }
    }

    // ---- per-row KNN from packed histogram ----
    float knn=0.f;
#pragma unroll
    for (int r=0;r<RPW;r++){
      u64 v=histp[wv][r][lane];
      u32 hh=(u32)(v>>44);
      float ll=(float)(v&0xFFFFFFFFFFFull)*5.9604645e-8f;  // 2^-24
      u32 inc=hh;
#pragma unroll
      for (int o=1;o<64;o<<=1){ u32 y=__shfl_up(inc,o,64); if (lane>=o) inc+=y; }
      int M=__shfl((int)inc,63,64);
      if (M<=32){
        knn+=wsum(ll);
      } else {
        u32 exc=inc-hh;
        bool sel=(exc<=32u)&&(inc>32u);
        u64 sm=__ballot(sel);
        int src=__ffsll(sm)-1;
        int rneed=__shfl(32-(int)exc,src,64);
        float bl=__shfl(ll,src,64);
        u32 bh=__shfl(hh,src,64);
        float below=wsum(lane<src?ll:0.f);
        knn+=below+(float)rneed*bl/(float)bh;
      }
    }

    float bqt=wsum(bqa);
#pragma unroll
    for (int r=0;r<RPW;r++){
      float ff=wsum(f1[r]);
      bqt+=(float)(64-min(cnt[r],64))*ff;
    }
    tknn+=knn; tbq+=bqt;
  }

  if (lane==0){ wred[wv][0]=tknn; wred[wv][1]=tbq; wred[wv][2]=dl; }
  __syncthreads();
  if (tid==0){
    float k=0.f,bb=0.f,dd=0.f;
#pragma unroll
    for (int w2=0;w2<WPB;w2++){ k+=wred[w2][0]; bb+=wred[w2][1]; dd+=wred[w2][2]; }
    part[bid*3]=k; part[bid*3+1]=bb; part[bid*3+2]=dd;
    __threadfence();
    u32 d=atomicAdd(&ctr[DONE_IDX],1u);
    lastf=(d==(u32)(NBLK-1))?1:0;
  }
  __syncthreads();
  // last-finishing block reduces all partials (fixed order -> deterministic)
  if (lastf && wv==0){
    __threadfence();
    double k=0.0,b2=0.0,d2=0.0;
    const volatile float* vp=(const volatile float*)part;
    for (int i=lane;i<NBLK;i+=64){ k+=vp[3*i]; b2+=vp[3*i+1]; d2+=vp[3*i+2]; }
#pragma unroll
    for (int o=32;o>0;o>>=1){
      k+=__shfl_xor(k,o,64); b2+=__shfl_xor(b2,o,64); d2+=__shfl_xor(d2,o,64);
    }
    if (lane==0){
      double knn=k/(32768.0*32.0), bq=b2/(32768.0*64.0), dat=d2/98304.0;
      out[0]=(float)(0.75*dat+0.25*(0.5*knn+0.5*bq));
    }
  }
}

// ---------------- fallback (verified round-1 kernel) ----------------
#define TILE 1024
#define FRPB 16
#define FRPW 4
__global__ void init_ws_k(double* ws){ int t=threadIdx.x; if(t<3) ws[t]=0.0; }
__global__ void fin_k(const double* __restrict__ ws, float* __restrict__ out){
  double knn = ws[0] / (32768.0*32.0);
  double bq  = ws[1] / (32768.0*64.0);
  double dat = ws[2] / 98304.0;
  out[0] = (float)(0.75*dat + 0.25*(0.5*knn + 0.5*bq));
}
__global__ __launch_bounds__(256) void fb_loss_k(
  const float* __restrict__ pc, const float* __restrict__ fl,
  const float* __restrict__ gt, double* __restrict__ ws)
{
  __shared__ float sx[TILE],sy[TILE],sz[TILE],sfx[TILE],sfy[TILE],sfz[TILE];
  __shared__ unsigned fhist[FRPB][64];
  __shared__ u64 fbkey[FRPB][64];
  __shared__ float fbl1v[FRPB][64];
  const int tid=threadIdx.x, lane=tid&63, wv=tid>>6, bid=blockIdx.x;
  const u64 lt=(1ull<<lane)-1ull;
  float dl=0.f;
  for (int e=bid*256+tid; e<NB*NPTS*3; e+=gridDim.x*256) dl+=fabsf(fl[e]-gt[e]);
  dl=wsum(dl);
  if (lane==0 && dl!=0.f) atomicAdd(ws+2,(double)dl);
  const int row0=bid*FRPB+wv*FRPW;
  const int b=row0/NPTS, i0=row0-b*NPTS;
  const float* pcb=pc+(size_t)b*NPTS*3;
  const float* flb=fl+(size_t)b*NPTS*3;
  float xi[FRPW],yi[FRPW],zi[FRPW],fxi[FRPW],fyi[FRPW],fzi[FRPW];
  int cnt[FRPW]; float bqa[FRPW], f1[FRPW];
#pragma unroll
  for (int r=0;r<FRPW;r++){
    int i=i0+r;
    xi[r]=pcb[3*i]; yi[r]=pcb[3*i+1]; zi[r]=pcb[3*i+2];
    fxi[r]=flb[3*i]; fyi[r]=flb[3*i+1]; fzi[r]=flb[3*i+2];
    cnt[r]=0; bqa[r]=0.f; f1[r]=0.f;
  }
  { unsigned* hp=&fhist[0][0];
    for (int h=tid; h<FRPB*64; h+=256) hp[h]=0u; }
  for (int t=0;t<NPTS/TILE;t++){
#pragma unroll
    for (int k=0;k<TILE/256;k++){
      int p=k*256+tid, g=t*TILE+p;
      sx[p]=pcb[3*g]; sy[p]=pcb[3*g+1]; sz[p]=pcb[3*g+2];
      sfx[p]=flb[3*g]; sfy[p]=flb[3*g+1]; sfz[p]=flb[3*g+2];
    }
    __syncthreads();
#pragma unroll
    for (int r=0;r<FRPW;r++){
      const int wrow=wv*FRPW+r;
#pragma unroll 4
      for (int it=0;it<TILE/64;it++){
        int jl=it*64+lane;
        float dx=sx[jl]-xi[r],dy=sy[jl]-yi[r],dz=sz[jl]-zi[r];
        float sq=fmaf(dx,dx,fmaf(dy,dy,dz*dz));
        bool in=sq<R2C;
        u64 m=__ballot(in);
        if (in){ int bin=min((int)(sq*BSC),63); atomicAdd(&fhist[wrow][bin],1u); }
        if (cnt[r]<64){
          if (in){
            int p=cnt[r]+__popcll(m&lt);
            if (p<64){
              float l1=fabsf(sfx[jl]-fxi[r])+fabsf(sfy[jl]-fyi[r])+fabsf(sfz[jl]-fzi[r]);
              bqa[r]+=l1;
              if (p==0) f1[r]=l1;
            }
          }
        }
        cnt[r]+=__popcll(m);
      }
    }
    __syncthreads();
  }
  int bstar[FRPW],rneed[FRPW];
#pragma unroll
  for (int r=0;r<FRPW;r++){
    const int wrow=wv*FRPW+r;
    unsigned h=fhist[wrow][lane];
    unsigned inc=h;
#pragma unroll
    for (int o=1;o<64;o<<=1){ unsigned y=__shfl_up(inc,o,64); if (lane>=o) inc+=y; }
    int M=__shfl((int)inc,63,64);
    if (M<=32){ bstar[r]=64; rneed[r]=0; }
    else{
      unsigned exc=inc-h;
      bool sel=(exc<=32u)&&(inc>32u);
      u64 sm=__ballot(sel);
      int src=__ffsll(sm)-1;
      bstar[r]=src;
      rneed[r]=__shfl(32-(int)exc,src,64);
    }
  }
  float knn=0.f; int bcnt[FRPW]={0,0,0,0};
  for (int t=0;t<NPTS/TILE;t++){
#pragma unroll
    for (int k=0;k<TILE/256;k++){
      int p=k*256+tid, g=t*TILE+p;
      sx[p]=pcb[3*g]; sy[p]=pcb[3*g+1]; sz[p]=pcb[3*g+2];
      sfx[p]=flb[3*g]; sfy[p]=flb[3*g+1]; sfz[p]=flb[3*g+2];
    }
    __syncthreads();
#pragma unroll
    for (int r=0;r<FRPW;r++){
      const int wrow=wv*FRPW+r;
#pragma unroll 4
      for (int it=0;it<TILE/64;it++){
        int jl=it*64+lane;
        float dx=sx[jl]-xi[r],dy=sy[jl]-yi[r],dz=sz[jl]-zi[r];
        float sq=fmaf(dx,dx,fmaf(dy,dy,dz*dz));
        bool in=sq<R2C;
        int bin=min((int)(sq*BSC),63);
        bool keep=in&&(bin<bstar[r]);
        bool isb=in&&(bin==bstar[r]);
        float l1=0.f;
        if (keep||isb)
          l1=fabsf(sfx[jl]-fxi[r])+fabsf(sfy[jl]-fyi[r])+fabsf(sfz[jl]-fzi[r]);
        if (keep) knn+=l1;
        u64 mb2=__ballot(isb);
        if (isb){
          int p=bcnt[r]+__popcll(mb2&lt);
          if (p<64){
            fbkey[wrow][p]=((u64)__float_as_uint(sq)<<32)|(unsigned)(t*TILE+jl);
            fbl1v[wrow][p]=l1;
          }
        }
        bcnt[r]+=__popcll(mb2);
      }
    }
    __syncthreads();
  }
#pragma unroll
  for (int r=0;r<FRPW;r++){
    const int wrow=wv*FRPW+r;
    int L=min(bcnt[r],64);
    u64 mykey=~0ull; float myl1=0.f;
    if (lane<L){ mykey=fbkey[wrow][lane]; myl1=fbl1v[wrow][lane]; }
    int rank=0;
    for (int q=0;q<L;q++) rank += (fbkey[wrow][q]<mykey)?1:0;
    if (lane<L && rank<rneed[r]) knn+=myl1;
  }
  knn=wsum(knn);
  float bqt=0.f;
#pragma unroll
  for (int r=0;r<FRPW;r++){
    float s=wsum(bqa[r]);
    float ff=wsum(f1[r]);
    s+=(float)(64-min(cnt[r],64))*ff;
    bqt+=s;
  }
  if (lane==0){
    atomicAdd(ws+0,(double)knn);
    atomicAdd(ws+1,(double)bqt);
  }
}

extern "C" void kernel_launch(void* const* d_in, const int* in_sizes, int n_in,
                              void* d_out, int out_size, void* d_ws, size_t ws_size,
                              hipStream_t stream) {
  (void)in_sizes; (void)n_in; (void)out_size;
  const float* pc = (const float*)d_in[0];   // pc_source
  const float* fl = (const float*)d_in[2];   // pred_flow
  const float* gt = (const float*)d_in[3];   // gt_flow
  float* out = (float*)d_out;
  char* w = (char*)d_ws;
  double* acc = (double*)w;

  const size_t SORT_OFF = 256;
  const size_t PB_OFF   = SORT_OFF + (size_t)NB*NPTS*16u;    // pA 512 KB -> 524544
  const size_t AABB_OFF = PB_OFF + (size_t)NB*NPTS*8u;       // pB 256 KB -> 786688
  const size_t PART_OFF = AABB_OFF + (size_t)NB*NGRP*6*2u;   // ab 12 KB -> 798976
  const size_t CTR_OFF  = PART_OFF + (size_t)NBLK*3*4u;      // 823552
  const size_t NEED     = CTR_OFF + (size_t)(NCTR*CSTRIDE+32)*4u; // 831872

  if (ws_size < NEED){
    hipLaunchKernelGGL(init_ws_k, dim3(1), dim3(64), 0, stream, acc);
    hipLaunchKernelGGL(fb_loss_k, dim3((NB*NPTS)/FRPB), dim3(256), 0, stream,
                       pc, fl, gt, acc);
    hipLaunchKernelGGL(fin_k, dim3(1), dim3(1), 0, stream, acc, out);
    return;
  }
  float4* pA = (float4*)(w+SORT_OFF);
  float2* pB = (float2*)(w+PB_OFF);
  unsigned short* ab = (unsigned short*)(w+AABB_OFF);
  float* part = (float*)(w+PART_OFF);
  u32* ctr = (u32*)(w+CTR_OFF);

  hipLaunchKernelGGL(sort_k, dim3(NB),   dim3(1024), 0, stream, pc, fl, pA, pB, ab, ctr);
  hipLaunchKernelGGL(main_k, dim3(NBLK), dim3(256),  0, stream,
                     fl, gt, pA, pB, ab, part, ctr, out);
}

// Round 17
// 102.691 us; speedup vs baseline: 1.2505x; 1.2505x over previous
//
#include <hip/hip_runtime.h>
#include <hip/hip_bf16.h>
#include <hip/hip_fp16.h>

#define NPTS 8192
#define NB 4
#define R2C 0.5625f
#define BSC (64.0f/0.5625f)
#define RPW 2      // rows per work unit
#define WPB 4      // waves per block
#define NGRP 256   // 32-pt groups per batch
#define NUNITS (NB*NPTS/RPW)   // 16384
#define GPB (NPTS/RPW)         // 4096 units per batch
#define NBLK 2048              // main_k grid
#define NCTR 64                // distributed steal counters
#define UPC (NUNITS/NCTR)      // 256 units per counter
#define CSTRIDE 32             // u32 stride between counters (128 B)

typedef unsigned char u8;
typedef unsigned u32;
typedef unsigned long long u64;

__device__ __forceinline__ float wsum(float v){
#pragma unroll
  for (int o=32;o>0;o>>=1) v += __shfl_xor(v,o,64);
  return v;
}
__device__ __forceinline__ float rfl(float v){
  return __int_as_float(__builtin_amdgcn_readfirstlane(__float_as_int(v)));
}
__device__ __forceinline__ int cellof(float x,float y,float z){
  int ix=min(15,max(0,(int)((x+5.f)*1.6f)));
  int iy=min(15,max(0,(int)((y+5.f)*1.6f)));
  int iz=min(15,max(0,(int)((z+5.f)*1.6f)));
  int sx=(ix&1)|((ix&2)<<2)|((ix&4)<<4)|((ix&8)<<6);
  int sy=(iy&1)|((iy&2)<<2)|((iy&4)<<4)|((iy&8)<<6);
  int sz=(iz&1)|((iz&2)<<2)|((iz&4)<<4)|((iz&8)<<6);
  return (sx<<2)|(sy<<1)|sz;
}
// orderable u32 <-> float (monotone), for atomicMin/Max-based AABB
__device__ __forceinline__ u32 om(float f){
  u32 u=__float_as_uint(f);
  return (u&0x80000000u)? ~u : (u|0x80000000u);
}
__device__ __forceinline__ float iom(u32 m){
  u32 u=(m&0x80000000u)? (m&0x7fffffffu) : ~m;
  return __uint_as_float(u);
}

// ---------------- zero: global hist + steal counters ----------------
__global__ void zero_k(u32* __restrict__ histg, u32* __restrict__ ctr){
  int t=blockIdx.x*1024+threadIdx.x;
  if (t<NB*4096) histg[t]=0u;
  if (t<NCTR*CSTRIDE) ctr[t]=0u;
}
// ---------------- hist: 32 blocks, full machine-width ----------------
__global__ __launch_bounds__(1024) void hist_k(const float* __restrict__ pc,
                                               u32* __restrict__ histg){
  int t=blockIdx.x*1024+threadIdx.x;       // 32768 threads = 1/pt
  int b=t>>13;
  float x=pc[3*t],y=pc[3*t+1],z=pc[3*t+2];
  atomicAdd(&histg[(b<<12)|cellof(x,y,z)],1u);
}

// ---------------- sort: scan + scatter + AABB (1 block/batch, 1024 thr) ----------
__global__ __launch_bounds__(1024) void sort_k(
    const float* __restrict__ pc, const float* __restrict__ fl,
    const u32* __restrict__ histg,
    float4* __restrict__ pA, float2* __restrict__ pB,
    unsigned short* __restrict__ ab){
  __shared__ u32 hist[4096];     // 16 KB
  __shared__ u32 amm[NGRP*6];    // 6 KB
  __shared__ u32 wsums[16];
  const int b=blockIdx.x, tid=threadIdx.x, lane=tid&63, wid=tid>>6;
  for (int i=tid;i<4096;i+=1024) hist[i]=histg[(b<<12)+i];
  for (int i=tid;i<NGRP*6;i+=1024) amm[i]=(i&1)?0u:0xFFFFFFFFu;  // even=min,odd=max
  __syncthreads();
  // hierarchical exclusive scan: 4 cells/thread -> wave scan -> wave-total prefix
  {
    u32 loc[4]; u32 run=0;
#pragma unroll
    for (int k=0;k<4;k++){ u32 v=hist[tid*4+k]; loc[k]=run; run+=v; }
    u32 inc=run;
#pragma unroll
    for (int o=1;o<64;o<<=1){ u32 y=__shfl_up(inc,o,64); if (lane>=o) inc+=y; }
    if (lane==63) wsums[wid]=inc;
    __syncthreads();
    u32 wbase=0;
    for (int i=0;i<wid;i++) wbase+=wsums[i];
    u32 tbase=wbase+inc-run;
#pragma unroll
    for (int k=0;k<4;k++) hist[tid*4+k]=tbase+loc[k];
  }
  __syncthreads();
  const float* pcb=pc+(size_t)b*NPTS*3;
  const float* flb=fl+(size_t)b*NPTS*3;
  for (int i=tid;i<NPTS;i+=1024){
    float x=pcb[3*i],y=pcb[3*i+1],z=pcb[3*i+2];
    int c=cellof(x,y,z);
    u32 pos=atomicAdd(&hist[c],1u);
    int d=b*NPTS+(int)pos;
    pA[d]=make_float4(x,y,z,flb[3*i]);
    pB[d]=make_float2(flb[3*i+1],flb[3*i+2]);
    int g=(int)(pos>>5);
    atomicMin(&amm[g*6+0],om(x)); atomicMax(&amm[g*6+1],om(x));
    atomicMin(&amm[g*6+2],om(y)); atomicMax(&amm[g*6+3],om(y));
    atomicMin(&amm[g*6+4],om(z)); atomicMax(&amm[g*6+5],om(z));
  }
  __syncthreads();
  if (tid<NGRP){
    unsigned short* p6=ab+(b*NGRP+tid)*6;
    p6[0]=__half_as_ushort(__float2half_rd(iom(amm[tid*6+0])));
    p6[1]=__half_as_ushort(__float2half_ru(iom(amm[tid*6+1])));
    p6[2]=__half_as_ushort(__float2half_rd(iom(amm[tid*6+2])));
    p6[3]=__half_as_ushort(__float2half_ru(iom(amm[tid*6+3])));
    p6[4]=__half_as_ushort(__float2half_rd(iom(amm[tid*6+4])));
    p6[5]=__half_as_ushort(__float2half_ru(iom(amm[tid*6+5])));
  }
}

// ---------------- final reduction ----------------
__global__ void finp_k(const float* __restrict__ part, float* __restrict__ out){
  int lane=threadIdx.x;
  double k=0.0,b=0.0,d=0.0;
  for (int i=lane;i<NBLK;i+=64){ k+=part[3*i]; b+=part[3*i+1]; d+=part[3*i+2]; }
#pragma unroll
  for (int o=32;o>0;o>>=1){
    k+=__shfl_xor(k,o,64); b+=__shfl_xor(b,o,64); d+=__shfl_xor(d,o,64);
  }
  if (lane==0){
    double knn=k/(32768.0*32.0), bq=b/(32768.0*64.0), dat=d/98304.0;
    out[0]=(float)(0.75*dat+0.25*(0.5*knn+0.5*bq));
  }
}

// ---------------- main loss kernel: single-pass, packed u64 hist, depth-2 prefetch ----
// Packed bin: count in [44:63], L1 fixed-point 2^-24 in [0:43].
__global__ __launch_bounds__(256,4) void main_k(
  const float* __restrict__ fl, const float* __restrict__ gt,
  const float4* __restrict__ gpA, const float2* __restrict__ gpB,
  const unsigned short* __restrict__ ab,
  float* __restrict__ part, u32* __restrict__ ctr)
{
  __shared__ unsigned short sab[NB][NGRP*6];   // 12 KB
  __shared__ u64  histp[WPB][RPW][64];         // 4 KB
  __shared__ u8   glg[WPB][NGRP];              // 1 KB
  __shared__ float wred[WPB][3];

  const int tid=threadIdx.x, lane=tid&63, wv=tid>>6, bid=blockIdx.x;
  const u64 lt=(1ull<<lane)-1ull;
  const bool lo=(lane<32);
  const int l5=lane&31;

  { const u32* s=(const u32*)ab;
    u32* d=(u32*)&sab[0][0];
    for (int k=tid;k<NB*NGRP*3;k+=256) d[k]=s[k]; }
  __syncthreads();

  // data loss (grid-stride)
  float dl=0.f;
  for (int e=bid*256+tid; e<NB*NPTS*3; e+=gridDim.x*256) dl+=fabsf(fl[e]-gt[e]);
  dl=wsum(dl);

  float tknn=0.f, tbq=0.f;
  int cp=bid&(NCTR-1);

  for (;;){
    int k;
    if (lane==0){
      u32 kk=atomicAdd(&ctr[cp*CSTRIDE],1u);
      if (kk>=UPC){
        kk=0x7fffffffu;
        int qb=cp&~3;
#pragma unroll
        for (int t=0;t<4;t++){
          int c2=qb+t;
          if (c2==cp) continue;
          u32 v=*(volatile u32*)&ctr[c2*CSTRIDE];
          if (v<UPC){
            u32 k2=atomicAdd(&ctr[c2*CSTRIDE],1u);
            if (k2<UPC){ cp=c2; kk=k2; break; }
          }
        }
      }
      k=(int)kk;
    }
    k=__shfl(k,0,64);
    cp=__shfl(cp,0,64);
    if (k>=UPC) break;
    const int u=cp+(k<<6);

    const int b=u>>12;
    const int i0=(u&(GPB-1))*RPW;
    const float4* pA=gpA+b*NPTS;
    const float2* pB=gpB+b*NPTS;

    float rx[RPW],ry[RPW],rz[RPW],rfx[RPW],rfy[RPW],rfz[RPW];
#pragma unroll
    for (int r=0;r<RPW;r++){
      float4 A=pA[i0+r]; float2 B=pB[i0+r];
      rx[r]=rfl(A.x); ry[r]=rfl(A.y); rz[r]=rfl(A.z);
      rfx[r]=rfl(A.w); rfy[r]=rfl(B.x); rfz[r]=rfl(B.y);
    }
    float wx0=rx[0],wx1=rx[0],wy0=ry[0],wy1=ry[0],wz0=rz[0],wz1=rz[0];
#pragma unroll
    for (int r=1;r<RPW;r++){
      wx0=fminf(wx0,rx[r]); wx1=fmaxf(wx1,rx[r]);
      wy0=fminf(wy0,ry[r]); wy1=fmaxf(wy1,ry[r]);
      wz0=fminf(wz0,rz[r]); wz1=fmaxf(wz1,rz[r]);
    }

    // classify 256 groups (lane handles h*64+lane) + ballot-compact ascending list
    int nsur;
    {
      int base=0;
#pragma unroll
      for (int h=0;h<4;h++){
        const unsigned short* a=&sab[b][(h*64+lane)*6];
        float gx0=__half2float(__ushort_as_half(a[0])), gx1=__half2float(__ushort_as_half(a[1]));
        float gy0=__half2float(__ushort_as_half(a[2])), gy1=__half2float(__ushort_as_half(a[3]));
        float gz0=__half2float(__ushort_as_half(a[4])), gz1=__half2float(__ushort_as_half(a[5]));
        float dxm=fmaxf(0.f,fmaxf(gx0-wx1,wx0-gx1));
        float dym=fmaxf(0.f,fmaxf(gy0-wy1,wy0-gy1));
        float dzm=fmaxf(0.f,fmaxf(gz0-wz1,wz0-gz1));
        float d2=fmaf(dxm,dxm,fmaf(dym,dym,dzm*dzm));
        bool c=d2<R2C;
        u64 bm=__ballot(c);
        if (c){ int p=base+__popcll(bm&lt); glg[wv][p]=(u8)(h*64+lane); }
        base+=__popcll(bm);
      }
      nsur=base;
    }
#pragma unroll
    for (int r=0;r<RPW;r++) histp[wv][r][lane]=0ull;

    // ---- single pass: packed count+L1 histogram + online ball query ----
    int cnt[RPW]; float f1[RPW]; float bqa=0.f;
#pragma unroll
    for (int r=0;r<RPW;r++){ cnt[r]=0; f1[r]=0.f; }
    {
      const int npair=(nsur+1)>>1;
      int s0=(0)|(lo?0:1);               // pair 0
      int jb=(int)glg[wv][min(s0,nsur-1)]*32+l5;
      float4 J=pA[jb]; float2 JF=pB[jb];
      int s1=(min(1,npair-1)<<1)|(lo?0:1);
      int jb1=(int)glg[wv][min(s1,nsur-1)]*32+l5;
      float4 N1=pA[jb1]; float2 NF1=pB[jb1];
#pragma unroll 1
      for (int t=0;t<npair;t++){
        int s2=(min(t+2,npair-1)<<1)|(lo?0:1);
        int jb2=(int)glg[wv][min(s2,nsur-1)]*32+l5;
        float4 N2=pA[jb2]; float2 NF2=pB[jb2];
        bool vld=lo||((t<<1)+1<nsur);
        bool open=false;
#pragma unroll
        for (int r=0;r<RPW;r++) open = open || (cnt[r]<64);
#pragma unroll
        for (int r=0;r<RPW;r++){
          float dx=rx[r]-J.x, dy=ry[r]-J.y, dz=rz[r]-J.z;
          float sq=fmaf(dx,dx,fmaf(dy,dy,dz*dz));
          bool in=(sq<R2C)&&vld;
          if (in){
            int bin=min((int)(sq*BSC),63);
            float l1=fabsf(J.w-rfx[r])+fabsf(JF.x-rfy[r])+fabsf(JF.y-rfz[r]);
            atomicAdd(&histp[wv][r][bin],(1ull<<44)+(u64)(l1*16777216.0f));
          }
          if (cnt[r]<64){
            u64 m=__ballot(in);
            if (in){
              int p=cnt[r]+__popcll(m&lt);
              if (p<64){
                float l1=fabsf(J.w-rfx[r])+fabsf(JF.x-rfy[r])+fabsf(JF.y-rfz[r]);
                bqa+=l1;
                if (p==0) f1[r]=l1;
              }
            }
            cnt[r]+=__popcll(m);
          }
        }
        J=N1; JF=NF1; N1=N2; NF1=NF2;
      }
    }

    // ---- per-row KNN from packed histogram ----
    float knn=0.f;
#pragma unroll
    for (int r=0;r<RPW;r++){
      u64 v=histp[wv][r][lane];
      u32 hh=(u32)(v>>44);
      float ll=(float)(v&0xFFFFFFFFFFFull)*5.9604645e-8f;  // 2^-24
      u32 inc=hh;
#pragma unroll
      for (int o=1;o<64;o<<=1){ u32 y=__shfl_up(inc,o,64); if (lane>=o) inc+=y; }
      int M=__shfl((int)inc,63,64);
      if (M<=32){
        knn+=wsum(ll);
      } else {
        u32 exc=inc-hh;
        bool sel=(exc<=32u)&&(inc>32u);
        u64 sm=__ballot(sel);
        int src=__ffsll(sm)-1;
        int rneed=__shfl(32-(int)exc,src,64);
        float bl=__shfl(ll,src,64);
        u32 bh=__shfl(hh,src,64);
        float below=wsum(lane<src?ll:0.f);
        knn+=below+(float)rneed*bl/(float)bh;
      }
    }

    float bqt=wsum(bqa);
#pragma unroll
    for (int r=0;r<RPW;r++){
      float ff=wsum(f1[r]);
      bqt+=(float)(64-min(cnt[r],64))*ff;
    }
    tknn+=knn; tbq+=bqt;
  }

  if (lane==0){ wred[wv][0]=tknn; wred[wv][1]=tbq; wred[wv][2]=dl; }
  __syncthreads();
  if (tid==0){
    float k=0.f,bb=0.f,dd=0.f;
#pragma unroll
    for (int w2=0;w2<WPB;w2++){ k+=wred[w2][0]; bb+=wred[w2][1]; dd+=wred[w2][2]; }
    part[bid*3]=k; part[bid*3+1]=bb; part[bid*3+2]=dd;
  }
}

// ---------------- fallback (verified round-1 kernel) ----------------
#define TILE 1024
#define FRPB 16
#define FRPW 4
__global__ void init_ws_k(double* ws){ int t=threadIdx.x; if(t<3) ws[t]=0.0; }
__global__ void fin_k(const double* __restrict__ ws, float* __restrict__ out){
  double knn = ws[0] / (32768.0*32.0);
  double bq  = ws[1] / (32768.0*64.0);
  double dat = ws[2] / 98304.0;
  out[0] = (float)(0.75*dat + 0.25*(0.5*knn + 0.5*bq));
}
__global__ __launch_bounds__(256) void fb_loss_k(
  const float* __restrict__ pc, const float* __restrict__ fl,
  const float* __restrict__ gt, double* __restrict__ ws)
{
  __shared__ float sx[TILE],sy[TILE],sz[TILE],sfx[TILE],sfy[TILE],sfz[TILE];
  __shared__ unsigned fhist[FRPB][64];
  __shared__ u64 fbkey[FRPB][64];
  __shared__ float fbl1v[FRPB][64];
  const int tid=threadIdx.x, lane=tid&63, wv=tid>>6, bid=blockIdx.x;
  const u64 lt=(1ull<<lane)-1ull;
  float dl=0.f;
  for (int e=bid*256+tid; e<NB*NPTS*3; e+=gridDim.x*256) dl+=fabsf(fl[e]-gt[e]);
  dl=wsum(dl);
  if (lane==0 && dl!=0.f) atomicAdd(ws+2,(double)dl);
  const int row0=bid*FRPB+wv*FRPW;
  const int b=row0/NPTS, i0=row0-b*NPTS;
  const float* pcb=pc+(size_t)b*NPTS*3;
  const float* flb=fl+(size_t)b*NPTS*3;
  float xi[FRPW],yi[FRPW],zi[FRPW],fxi[FRPW],fyi[FRPW],fzi[FRPW];
  int cnt[FRPW]; float bqa[FRPW], f1[FRPW];
#pragma unroll
  for (int r=0;r<FRPW;r++){
    int i=i0+r;
    xi[r]=pcb[3*i]; yi[r]=pcb[3*i+1]; zi[r]=pcb[3*i+2];
    fxi[r]=flb[3*i]; fyi[r]=flb[3*i+1]; fzi[r]=flb[3*i+2];
    cnt[r]=0; bqa[r]=0.f; f1[r]=0.f;
  }
  { unsigned* hp=&fhist[0][0];
    for (int h=tid; h<FRPB*64; h+=256) hp[h]=0u; }
  for (int t=0;t<NPTS/TILE;t++){
#pragma unroll
    for (int k=0;k<TILE/256;k++){
      int p=k*256+tid, g=t*TILE+p;
      sx[p]=pcb[3*g]; sy[p]=pcb[3*g+1]; sz[p]=pcb[3*g+2];
      sfx[p]=flb[3*g]; sfy[p]=flb[3*g+1]; sfz[p]=flb[3*g+2];
    }
    __syncthreads();
#pragma unroll
    for (int r=0;r<FRPW;r++){
      const int wrow=wv*FRPW+r;
#pragma unroll 4
      for (int it=0;it<TILE/64;it++){
        int jl=it*64+lane;
        float dx=sx[jl]-xi[r],dy=sy[jl]-yi[r],dz=sz[jl]-zi[r];
        float sq=fmaf(dx,dx,fmaf(dy,dy,dz*dz));
        bool in=sq<R2C;
        u64 m=__ballot(in);
        if (in){ int bin=min((int)(sq*BSC),63); atomicAdd(&fhist[wrow][bin],1u); }
        if (cnt[r]<64){
          if (in){
            int p=cnt[r]+__popcll(m&lt);
            if (p<64){
              float l1=fabsf(sfx[jl]-fxi[r])+fabsf(sfy[jl]-fyi[r])+fabsf(sfz[jl]-fzi[r]);
              bqa[r]+=l1;
              if (p==0) f1[r]=l1;
            }
          }
        }
        cnt[r]+=__popcll(m);
      }
    }
    __syncthreads();
  }
  int bstar[FRPW],rneed[FRPW];
#pragma unroll
  for (int r=0;r<FRPW;r++){
    const int wrow=wv*FRPW+r;
    unsigned h=fhist[wrow][lane];
    unsigned inc=h;
#pragma unroll
    for (int o=1;o<64;o<<=1){ unsigned y=__shfl_up(inc,o,64); if (lane>=o) inc+=y; }
    int M=__shfl((int)inc,63,64);
    if (M<=32){ bstar[r]=64; rneed[r]=0; }
    else{
      unsigned exc=inc-h;
      bool sel=(exc<=32u)&&(inc>32u);
      u64 sm=__ballot(sel);
      int src=__ffsll(sm)-1;
      bstar[r]=src;
      rneed[r]=__shfl(32-(int)exc,src,64);
    }
  }
  float knn=0.f; int bcnt[FRPW]={0,0,0,0};
  for (int t=0;t<NPTS/TILE;t++){
#pragma unroll
    for (int k=0;k<TILE/256;k++){
      int p=k*256+tid, g=t*TILE+p;
      sx[p]=pcb[3*g]; sy[p]=pcb[3*g+1]; sz[p]=pcb[3*g+2];
      sfx[p]=flb[3*g]; sfy[p]=flb[3*g+1]; sfz[p]=flb[3*g+2];
    }
    __syncthreads();
#pragma unroll
    for (int r=0;r<FRPW;r++){
      const int wrow=wv*FRPW+r;
#pragma unroll 4
      for (int it=0;it<TILE/64;it++){
        int jl=it*64+lane;
        float dx=sx[jl]-xi[r],dy=sy[jl]-yi[r],dz=sz[jl]-zi[r];
        float sq=fmaf(dx,dx,fmaf(dy,dy,dz*dz));
        bool in=sq<R2C;
        int bin=min((int)(sq*BSC),63);
        bool keep=in&&(bin<bstar[r]);
        bool isb=in&&(bin==bstar[r]);
        float l1=0.f;
        if (keep||isb)
          l1=fabsf(sfx[jl]-fxi[r])+fabsf(sfy[jl]-fyi[r])+fabsf(sfz[jl]-fzi[r]);
        if (keep) knn+=l1;
        u64 mb2=__ballot(isb);
        if (isb){
          int p=bcnt[r]+__popcll(mb2&lt);
          if (p<64){
            fbkey[wrow][p]=((u64)__float_as_uint(sq)<<32)|(unsigned)(t*TILE+jl);
            fbl1v[wrow][p]=l1;
          }
        }
        bcnt[r]+=__popcll(mb2);
      }
    }
    __syncthreads();
  }
#pragma unroll
  for (int r=0;r<FRPW;r++){
    const int wrow=wv*FRPW+r;
    int L=min(bcnt[r],64);
    u64 mykey=~0ull; float myl1=0.f;
    if (lane<L){ mykey=fbkey[wrow][lane]; myl1=fbl1v[wrow][lane]; }
    int rank=0;
    for (int q=0;q<L;q++) rank += (fbkey[wrow][q]<mykey)?1:0;
    if (lane<L && rank<rneed[r]) knn+=myl1;
  }
  knn=wsum(knn);
  float bqt=0.f;
#pragma unroll
  for (int r=0;r<FRPW;r++){
    float s=wsum(bqa[r]);
    float ff=wsum(f1[r]);
    s+=(float)(64-min(cnt[r],64))*ff;
    bqt+=s;
  }
  if (lane==0){
    atomicAdd(ws+0,(double)knn);
    atomicAdd(ws+1,(double)bqt);
  }
}

extern "C" void kernel_launch(void* const* d_in, const int* in_sizes, int n_in,
                              void* d_out, int out_size, void* d_ws, size_t ws_size,
                              hipStream_t stream) {
  (void)in_sizes; (void)n_in; (void)out_size;
  const float* pc = (const float*)d_in[0];   // pc_source
  const float* fl = (const float*)d_in[2];   // pred_flow
  const float* gt = (const float*)d_in[3];   // gt_flow
  float* out = (float*)d_out;
  char* w = (char*)d_ws;
  double* acc = (double*)w;

  const size_t SORT_OFF = 256;
  const size_t PB_OFF   = SORT_OFF + (size_t)NB*NPTS*16u;    // pA 512 KB -> 524544
  const size_t AABB_OFF = PB_OFF + (size_t)NB*NPTS*8u;       // pB 256 KB -> 786688
  const size_t HIST_OFF = AABB_OFF + (size_t)NB*NGRP*6*2u;   // ab 12 KB -> 798976
  const size_t PART_OFF = HIST_OFF + (size_t)NB*4096*4u;     // hist 64 KB -> 864512
  const size_t CTR_OFF  = PART_OFF + (size_t)NBLK*3*4u;      // 889088
  const size_t NEED     = CTR_OFF + (size_t)NCTR*CSTRIDE*4u; // 897280

  if (ws_size < NEED){
    hipLaunchKernelGGL(init_ws_k, dim3(1), dim3(64), 0, stream, acc);
    hipLaunchKernelGGL(fb_loss_k, dim3((NB*NPTS)/FRPB), dim3(256), 0, stream,
                       pc, fl, gt, acc);
    hipLaunchKernelGGL(fin_k, dim3(1), dim3(1), 0, stream, acc, out);
    return;
  }
  float4* pA = (float4*)(w+SORT_OFF);
  float2* pB = (float2*)(w+PB_OFF);
  unsigned short* ab = (unsigned short*)(w+AABB_OFF);
  u32* histg = (u32*)(w+HIST_OFF);
  float* part = (float*)(w+PART_OFF);
  u32* ctr = (u32*)(w+CTR_OFF);

  hipLaunchKernelGGL(zero_k, dim3(16),  dim3(1024), 0, stream, histg, ctr);
  hipLaunchKernelGGL(hist_k, dim3(32),  dim3(1024), 0, stream, pc, histg);
  hipLaunchKernelGGL(sort_k, dim3(NB),  dim3(1024), 0, stream, pc, fl, histg, pA, pB, ab);
  hipLaunchKernelGGL(main_k, dim3(NBLK), dim3(256), 0, stream,
                     fl, gt, pA, pB, ab, part, ctr);
  hipLaunchKernelGGL(finp_k, dim3(1), dim3(64), 0, stream, part, out);
}

// Round 18
// 95.358 us; speedup vs baseline: 1.3467x; 1.0769x over previous
//
#include <hip/hip_runtime.h>
#include <hip/hip_bf16.h>
#include <hip/hip_fp16.h>

#define NPTS 8192
#define NB 4
#define R2C 0.5625f
#define BSC (64.0f/0.5625f)
#define RPW 2      // rows per work unit
#define WPB 4      // waves per block
#define NGRP 256   // 32-pt groups per batch
#define NUNITS (NB*NPTS/RPW)   // 16384
#define GPB (NPTS/RPW)         // 4096 units per batch
#define NBLK 2048              // main_k grid
#define NCTR 64                // distributed steal counters
#define UPC (NUNITS/NCTR)      // 256 units per counter
#define CSTRIDE 32             // u32 stride between counters (128 B)

typedef unsigned char u8;
typedef unsigned u32;
typedef unsigned long long u64;

__device__ __forceinline__ float wsum(float v){
#pragma unroll
  for (int o=32;o>0;o>>=1) v += __shfl_xor(v,o,64);
  return v;
}
__device__ __forceinline__ float rfl(float v){
  return __int_as_float(__builtin_amdgcn_readfirstlane(__float_as_int(v)));
}
__device__ __forceinline__ int cellof(float x,float y,float z){
  int ix=min(15,max(0,(int)((x+5.f)*1.6f)));
  int iy=min(15,max(0,(int)((y+5.f)*1.6f)));
  int iz=min(15,max(0,(int)((z+5.f)*1.6f)));
  int sx=(ix&1)|((ix&2)<<2)|((ix&4)<<4)|((ix&8)<<6);
  int sy=(iy&1)|((iy&2)<<2)|((iy&4)<<4)|((iy&8)<<6);
  int sz=(iz&1)|((iz&2)<<2)|((iz&4)<<4)|((iz&8)<<6);
  return (sx<<2)|(sy<<1)|sz;
}
// orderable u32 <-> float (monotone), for atomicMin/Max-based AABB
__device__ __forceinline__ u32 om(float f){
  u32 u=__float_as_uint(f);
  return (u&0x80000000u)? ~u : (u|0x80000000u);
}
__device__ __forceinline__ float iom(u32 m){
  u32 u=(m&0x80000000u)? (m&0x7fffffffu) : ~m;
  return __uint_as_float(u);
}

// ---------------- fused sort pipeline (1024 threads/block, wave-parallel scan) ----
__global__ __launch_bounds__(1024) void sort_k(
    const float* __restrict__ pc, const float* __restrict__ fl,
    float4* __restrict__ pA, float2* __restrict__ pB,
    unsigned short* __restrict__ ab, u32* __restrict__ ctr){
  __shared__ u32 hist[4096];     // 16 KB
  __shared__ u32 amm[NGRP*6];    // 6 KB
  __shared__ u32 wsums[16];
  const int b=blockIdx.x, tid=threadIdx.x, lane=tid&63, wid=tid>>6;
  for (int i=tid;i<4096;i+=1024) hist[i]=0u;
  for (int i=tid;i<NGRP*6;i+=1024) amm[i]=(i&1)?0u:0xFFFFFFFFu;  // even=min,odd=max
  if (b==0) for (int i=tid;i<NCTR*CSTRIDE;i+=1024) ctr[i]=0u;
  __syncthreads();
  const float* pcb=pc+(size_t)b*NPTS*3;
  const float* flb=fl+(size_t)b*NPTS*3;
  for (int i=tid;i<NPTS;i+=1024){
    float x=pcb[3*i],y=pcb[3*i+1],z=pcb[3*i+2];
    atomicAdd(&hist[cellof(x,y,z)],1u);
  }
  __syncthreads();
  // hierarchical exclusive scan: 4 cells/thread -> wave scan -> wave-total prefix
  {
    u32 loc[4]; u32 run=0;
#pragma unroll
    for (int k=0;k<4;k++){ u32 v=hist[tid*4+k]; loc[k]=run; run+=v; }
    u32 inc=run;
#pragma unroll
    for (int o=1;o<64;o<<=1){ u32 y=__shfl_up(inc,o,64); if (lane>=o) inc+=y; }
    if (lane==63) wsums[wid]=inc;
    __syncthreads();
    u32 wbase=0;
    for (int i=0;i<wid;i++) wbase+=wsums[i];
    u32 tbase=wbase+inc-run;
#pragma unroll
    for (int k=0;k<4;k++) hist[tid*4+k]=tbase+loc[k];
  }
  __syncthreads();
  for (int i=tid;i<NPTS;i+=1024){
    float x=pcb[3*i],y=pcb[3*i+1],z=pcb[3*i+2];
    int c=cellof(x,y,z);
    u32 pos=atomicAdd(&hist[c],1u);
    int d=b*NPTS+(int)pos;
    pA[d]=make_float4(x,y,z,flb[3*i]);
    pB[d]=make_float2(flb[3*i+1],flb[3*i+2]);
    int g=(int)(pos>>5);
    atomicMin(&amm[g*6+0],om(x)); atomicMax(&amm[g*6+1],om(x));
    atomicMin(&amm[g*6+2],om(y)); atomicMax(&amm[g*6+3],om(y));
    atomicMin(&amm[g*6+4],om(z)); atomicMax(&amm[g*6+5],om(z));
  }
  __syncthreads();
  if (tid<NGRP){
    unsigned short* p6=ab+(b*NGRP+tid)*6;
    p6[0]=__half_as_ushort(__float2half_rd(iom(amm[tid*6+0])));
    p6[1]=__half_as_ushort(__float2half_ru(iom(amm[tid*6+1])));
    p6[2]=__half_as_ushort(__float2half_rd(iom(amm[tid*6+2])));
    p6[3]=__half_as_ushort(__float2half_ru(iom(amm[tid*6+3])));
    p6[4]=__half_as_ushort(__float2half_rd(iom(amm[tid*6+4])));
    p6[5]=__half_as_ushort(__float2half_ru(iom(amm[tid*6+5])));
  }
}

// ---------------- final reduction ----------------
__global__ void finp_k(const float* __restrict__ part, float* __restrict__ out){
  int lane=threadIdx.x;
  double k=0.0,b=0.0,d=0.0;
  for (int i=lane;i<NBLK;i+=64){ k+=part[3*i]; b+=part[3*i+1]; d+=part[3*i+2]; }
#pragma unroll
  for (int o=32;o>0;o>>=1){
    k+=__shfl_xor(k,o,64); b+=__shfl_xor(b,o,64); d+=__shfl_xor(d,o,64);
  }
  if (lane==0){
    double knn=k/(32768.0*32.0), bq=b/(32768.0*64.0), dat=d/98304.0;
    out[0]=(float)(0.75*dat+0.25*(0.5*knn+0.5*bq));
  }
}

// ---------------- main loss kernel: single-pass, packed u64 hist, depth-2 prefetch ----
// Packed bin: count in [44:63], L1 fixed-point 2^-24 in [0:43].
__global__ __launch_bounds__(256,4) void main_k(
  const float* __restrict__ fl, const float* __restrict__ gt,
  const float4* __restrict__ gpA, const float2* __restrict__ gpB,
  const unsigned short* __restrict__ ab,
  float* __restrict__ part, u32* __restrict__ ctr)
{
  __shared__ unsigned short sab[NB][NGRP*6];   // 12 KB
  __shared__ u64  histp[WPB][RPW][64];         // 4 KB
  __shared__ u8   glg[WPB][NGRP];              // 1 KB
  __shared__ float wred[WPB][3];

  const int tid=threadIdx.x, lane=tid&63, wv=tid>>6, bid=blockIdx.x;
  const u64 lt=(1ull<<lane)-1ull;
  const bool lo=(lane<32);
  const int l5=lane&31;

  { const u32* s=(const u32*)ab;
    u32* d=(u32*)&sab[0][0];
    for (int k=tid;k<NB*NGRP*3;k+=256) d[k]=s[k]; }
  __syncthreads();

  // data loss (grid-stride)
  float dl=0.f;
  for (int e=bid*256+tid; e<NB*NPTS*3; e+=gridDim.x*256) dl+=fabsf(fl[e]-gt[e]);
  dl=wsum(dl);

  float tknn=0.f, tbq=0.f;
  int cp=bid&(NCTR-1);

  for (;;){
    int k;
    if (lane==0){
      u32 kk=atomicAdd(&ctr[cp*CSTRIDE],1u);
      if (kk>=UPC){
        kk=0x7fffffffu;
        int qb=cp&~3;
#pragma unroll
        for (int t=0;t<4;t++){
          int c2=qb+t;
          if (c2==cp) continue;
          u32 v=*(volatile u32*)&ctr[c2*CSTRIDE];
          if (v<UPC){
            u32 k2=atomicAdd(&ctr[c2*CSTRIDE],1u);
            if (k2<UPC){ cp=c2; kk=k2; break; }
          }
        }
      }
      k=(int)kk;
    }
    k=__shfl(k,0,64);
    cp=__shfl(cp,0,64);
    if (k>=UPC) break;
    const int u=cp+(k<<6);

    const int b=u>>12;
    const int i0=(u&(GPB-1))*RPW;
    const float4* pA=gpA+b*NPTS;
    const float2* pB=gpB+b*NPTS;

    float rx[RPW],ry[RPW],rz[RPW],rfx[RPW],rfy[RPW],rfz[RPW];
#pragma unroll
    for (int r=0;r<RPW;r++){
      float4 A=pA[i0+r]; float2 B=pB[i0+r];
      rx[r]=rfl(A.x); ry[r]=rfl(A.y); rz[r]=rfl(A.z);
      rfx[r]=rfl(A.w); rfy[r]=rfl(B.x); rfz[r]=rfl(B.y);
    }
    float wx0=rx[0],wx1=rx[0],wy0=ry[0],wy1=ry[0],wz0=rz[0],wz1=rz[0];
#pragma unroll
    for (int r=1;r<RPW;r++){
      wx0=fminf(wx0,rx[r]); wx1=fmaxf(wx1,rx[r]);
      wy0=fminf(wy0,ry[r]); wy1=fmaxf(wy1,ry[r]);
      wz0=fminf(wz0,rz[r]); wz1=fmaxf(wz1,rz[r]);
    }

    // classify 256 groups (lane handles h*64+lane) + ballot-compact ascending list
    int nsur;
    {
      int base=0;
#pragma unroll
      for (int h=0;h<4;h++){
        const unsigned short* a=&sab[b][(h*64+lane)*6];
        float gx0=__half2float(__ushort_as_half(a[0])), gx1=__half2float(__ushort_as_half(a[1]));
        float gy0=__half2float(__ushort_as_half(a[2])), gy1=__half2float(__ushort_as_half(a[3]));
        float gz0=__half2float(__ushort_as_half(a[4])), gz1=__half2float(__ushort_as_half(a[5]));
        float dxm=fmaxf(0.f,fmaxf(gx0-wx1,wx0-gx1));
        float dym=fmaxf(0.f,fmaxf(gy0-wy1,wy0-gy1));
        float dzm=fmaxf(0.f,fmaxf(gz0-wz1,wz0-gz1));
        float d2=fmaf(dxm,dxm,fmaf(dym,dym,dzm*dzm));
        bool c=d2<R2C;
        u64 bm=__ballot(c);
        if (c){ int p=base+__popcll(bm&lt); glg[wv][p]=(u8)(h*64+lane); }
        base+=__popcll(bm);
      }
      nsur=base;
    }
#pragma unroll
    for (int r=0;r<RPW;r++) histp[wv][r][lane]=0ull;

    // ---- single pass: packed count+L1 histogram + online ball query ----
    int cnt[RPW]; float f1[RPW]; float bqa=0.f;
#pragma unroll
    for (int r=0;r<RPW;r++){ cnt[r]=0; f1[r]=0.f; }
    {
      const int npair=(nsur+1)>>1;
      int s0=(0)|(lo?0:1);               // pair 0
      int jb=(int)glg[wv][min(s0,nsur-1)]*32+l5;
      float4 J=pA[jb]; float2 JF=pB[jb];
      int s1=(min(1,npair-1)<<1)|(lo?0:1);
      int jb1=(int)glg[wv][min(s1,nsur-1)]*32+l5;
      float4 N1=pA[jb1]; float2 NF1=pB[jb1];
#pragma unroll 1
      for (int t=0;t<npair;t++){
        int s2=(min(t+2,npair-1)<<1)|(lo?0:1);
        int jb2=(int)glg[wv][min(s2,nsur-1)]*32+l5;
        float4 N2=pA[jb2]; float2 NF2=pB[jb2];
        bool vld=lo||((t<<1)+1<nsur);
        bool open=false;
#pragma unroll
        for (int r=0;r<RPW;r++) open = open || (cnt[r]<64);
#pragma unroll
        for (int r=0;r<RPW;r++){
          float dx=rx[r]-J.x, dy=ry[r]-J.y, dz=rz[r]-J.z;
          float sq=fmaf(dx,dx,fmaf(dy,dy,dz*dz));
          bool in=(sq<R2C)&&vld;
          if (in){
            int bin=min((int)(sq*BSC),63);
            float l1=fabsf(J.w-rfx[r])+fabsf(JF.x-rfy[r])+fabsf(JF.y-rfz[r]);
            atomicAdd(&histp[wv][r][bin],(1ull<<44)+(u64)(l1*16777216.0f));
          }
          if (cnt[r]<64){
            u64 m=__ballot(in);
            if (in){
              int p=cnt[r]+__popcll(m&lt);
              if (p<64){
                float l1=fabsf(J.w-rfx[r])+fabsf(JF.x-rfy[r])+fabsf(JF.y-rfz[r]);
                bqa+=l1;
                if (p==0) f1[r]=l1;
              }
            }
            cnt[r]+=__popcll(m);
          }
        }
        J=N1; JF=NF1; N1=N2; NF1=NF2;
      }
    }

    // ---- per-row KNN from packed histogram ----
    float knn=0.f;
#pragma unroll
    for (int r=0;r<RPW;r++){
      u64 v=histp[wv][r][lane];
      u32 hh=(u32)(v>>44);
      float ll=(float)(v&0xFFFFFFFFFFFull)*5.9604645e-8f;  // 2^-24
      u32 inc=hh;
#pragma unroll
      for (int o=1;o<64;o<<=1){ u32 y=__shfl_up(inc,o,64); if (lane>=o) inc+=y; }
      int M=__shfl((int)inc,63,64);
      if (M<=32){
        knn+=wsum(ll);
      } else {
        u32 exc=inc-hh;
        bool sel=(exc<=32u)&&(inc>32u);
        u64 sm=__ballot(sel);
        int src=__ffsll(sm)-1;
        int rneed=__shfl(32-(int)exc,src,64);
        float bl=__shfl(ll,src,64);
        u32 bh=__shfl(hh,src,64);
        float below=wsum(lane<src?ll:0.f);
        knn+=below+(float)rneed*bl/(float)bh;
      }
    }

    float bqt=wsum(bqa);
#pragma unroll
    for (int r=0;r<RPW;r++){
      float ff=wsum(f1[r]);
      bqt+=(float)(64-min(cnt[r],64))*ff;
    }
    tknn+=knn; tbq+=bqt;
  }

  if (lane==0){ wred[wv][0]=tknn; wred[wv][1]=tbq; wred[wv][2]=dl; }
  __syncthreads();
  if (tid==0){
    float k=0.f,bb=0.f,dd=0.f;
#pragma unroll
    for (int w2=0;w2<WPB;w2++){ k+=wred[w2][0]; bb+=wred[w2][1]; dd+=wred[w2][2]; }
    part[bid*3]=k; part[bid*3+1]=bb; part[bid*3+2]=dd;
  }
}

// ---------------- fallback (verified round-1 kernel) ----------------
#define TILE 1024
#define FRPB 16
#define FRPW 4
__global__ void init_ws_k(double* ws){ int t=threadIdx.x; if(t<3) ws[t]=0.0; }
__global__ void fin_k(const double* __restrict__ ws, float* __restrict__ out){
  double knn = ws[0] / (32768.0*32.0);
  double bq  = ws[1] / (32768.0*64.0);
  double dat = ws[2] / 98304.0;
  out[0] = (float)(0.75*dat + 0.25*(0.5*knn + 0.5*bq));
}
__global__ __launch_bounds__(256) void fb_loss_k(
  const float* __restrict__ pc, const float* __restrict__ fl,
  const float* __restrict__ gt, double* __restrict__ ws)
{
  __shared__ float sx[TILE],sy[TILE],sz[TILE],sfx[TILE],sfy[TILE],sfz[TILE];
  __shared__ unsigned fhist[FRPB][64];
  __shared__ u64 fbkey[FRPB][64];
  __shared__ float fbl1v[FRPB][64];
  const int tid=threadIdx.x, lane=tid&63, wv=tid>>6, bid=blockIdx.x;
  const u64 lt=(1ull<<lane)-1ull;
  float dl=0.f;
  for (int e=bid*256+tid; e<NB*NPTS*3; e+=gridDim.x*256) dl+=fabsf(fl[e]-gt[e]);
  dl=wsum(dl);
  if (lane==0 && dl!=0.f) atomicAdd(ws+2,(double)dl);
  const int row0=bid*FRPB+wv*FRPW;
  const int b=row0/NPTS, i0=row0-b*NPTS;
  const float* pcb=pc+(size_t)b*NPTS*3;
  const float* flb=fl+(size_t)b*NPTS*3;
  float xi[FRPW],yi[FRPW],zi[FRPW],fxi[FRPW],fyi[FRPW],fzi[FRPW];
  int cnt[FRPW]; float bqa[FRPW], f1[FRPW];
#pragma unroll
  for (int r=0;r<FRPW;r++){
    int i=i0+r;
    xi[r]=pcb[3*i]; yi[r]=pcb[3*i+1]; zi[r]=pcb[3*i+2];
    fxi[r]=flb[3*i]; fyi[r]=flb[3*i+1]; fzi[r]=flb[3*i+2];
    cnt[r]=0; bqa[r]=0.f; f1[r]=0.f;
  }
  { unsigned* hp=&fhist[0][0];
    for (int h=tid; h<FRPB*64; h+=256) hp[h]=0u; }
  for (int t=0;t<NPTS/TILE;t++){
#pragma unroll
    for (int k=0;k<TILE/256;k++){
      int p=k*256+tid, g=t*TILE+p;
      sx[p]=pcb[3*g]; sy[p]=pcb[3*g+1]; sz[p]=pcb[3*g+2];
      sfx[p]=flb[3*g]; sfy[p]=flb[3*g+1]; sfz[p]=flb[3*g+2];
    }
    __syncthreads();
#pragma unroll
    for (int r=0;r<FRPW;r++){
      const int wrow=wv*FRPW+r;
#pragma unroll 4
      for (int it=0;it<TILE/64;it++){
        int jl=it*64+lane;
        float dx=sx[jl]-xi[r],dy=sy[jl]-yi[r],dz=sz[jl]-zi[r];
        float sq=fmaf(dx,dx,fmaf(dy,dy,dz*dz));
        bool in=sq<R2C;
        u64 m=__ballot(in);
        if (in){ int bin=min((int)(sq*BSC),63); atomicAdd(&fhist[wrow][bin],1u); }
        if (cnt[r]<64){
          if (in){
            int p=cnt[r]+__popcll(m&lt);
            if (p<64){
              float l1=fabsf(sfx[jl]-fxi[r])+fabsf(sfy[jl]-fyi[r])+fabsf(sfz[jl]-fzi[r]);
              bqa[r]+=l1;
              if (p==0) f1[r]=l1;
            }
          }
        }
        cnt[r]+=__popcll(m);
      }
    }
    __syncthreads();
  }
  int bstar[FRPW],rneed[FRPW];
#pragma unroll
  for (int r=0;r<FRPW;r++){
    const int wrow=wv*FRPW+r;
    unsigned h=fhist[wrow][lane];
    unsigned inc=h;
#pragma unroll
    for (int o=1;o<64;o<<=1){ unsigned y=__shfl_up(inc,o,64); if (lane>=o) inc+=y; }
    int M=__shfl((int)inc,63,64);
    if (M<=32){ bstar[r]=64; rneed[r]=0; }
    else{
      unsigned exc=inc-h;
      bool sel=(exc<=32u)&&(inc>32u);
      u64 sm=__ballot(sel);
      int src=__ffsll(sm)-1;
      bstar[r]=src;
      rneed[r]=__shfl(32-(int)exc,src,64);
    }
  }
  float knn=0.f; int bcnt[FRPW]={0,0,0,0};
  for (int t=0;t<NPTS/TILE;t++){
#pragma unroll
    for (int k=0;k<TILE/256;k++){
      int p=k*256+tid, g=t*TILE+p;
      sx[p]=pcb[3*g]; sy[p]=pcb[3*g+1]; sz[p]=pcb[3*g+2];
      sfx[p]=flb[3*g]; sfy[p]=flb[3*g+1]; sfz[p]=flb[3*g+2];
    }
    __syncthreads();
#pragma unroll
    for (int r=0;r<FRPW;r++){
      const int wrow=wv*FRPW+r;
#pragma unroll 4
      for (int it=0;it<TILE/64;it++){
        int jl=it*64+lane;
        float dx=sx[jl]-xi[r],dy=sy[jl]-yi[r],dz=sz[jl]-zi[r];
        float sq=fmaf(dx,dx,fmaf(dy,dy,dz*dz));
        bool in=sq<R2C;
        int bin=min((int)(sq*BSC),63);
        bool keep=in&&(bin<bstar[r]);
        bool isb=in&&(bin==bstar[r]);
        float l1=0.f;
        if (keep||isb)
          l1=fabsf(sfx[jl]-fxi[r])+fabsf(sfy[jl]-fyi[r])+fabsf(sfz[jl]-fzi[r]);
        if (keep) knn+=l1;
        u64 mb2=__ballot(isb);
        if (isb){
          int p=bcnt[r]+__popcll(mb2&lt);
          if (p<64){
            fbkey[wrow][p]=((u64)__float_as_uint(sq)<<32)|(unsigned)(t*TILE+jl);
            fbl1v[wrow][p]=l1;
          }
        }
        bcnt[r]+=__popcll(mb2);
      }
    }
    __syncthreads();
  }
#pragma unroll
  for (int r=0;r<FRPW;r++){
    const int wrow=wv*FRPW+r;
    int L=min(bcnt[r],64);
    u64 mykey=~0ull; float myl1=0.f;
    if (lane<L){ mykey=fbkey[wrow][lane]; myl1=fbl1v[wrow][lane]; }
    int rank=0;
    for (int q=0;q<L;q++) rank += (fbkey[wrow][q]<mykey)?1:0;
    if (lane<L && rank<rneed[r]) knn+=myl1;
  }
  knn=wsum(knn);
  float bqt=0.f;
#pragma unroll
  for (int r=0;r<FRPW;r++){
    float s=wsum(bqa[r]);
    float ff=wsum(f1[r]);
    s+=(float)(64-min(cnt[r],64))*ff;
    bqt+=s;
  }
  if (lane==0){
    atomicAdd(ws+0,(double)knn);
    atomicAdd(ws+1,(double)bqt);
  }
}

extern "C" void kernel_launch(void* const* d_in, const int* in_sizes, int n_in,
                              void* d_out, int out_size, void* d_ws, size_t ws_size,
                              hipStream_t stream) {
  (void)in_sizes; (void)n_in; (void)out_size;
  const float* pc = (const float*)d_in[0];   // pc_source
  const float* fl = (const float*)d_in[2];   // pred_flow
  const float* gt = (const float*)d_in[3];   // gt_flow
  float* out = (float*)d_out;
  char* w = (char*)d_ws;
  double* acc = (double*)w;

  const size_t SORT_OFF = 256;
  const size_t PB_OFF   = SORT_OFF + (size_t)NB*NPTS*16u;    // pA 512 KB -> 524544
  const size_t AABB_OFF = PB_OFF + (size_t)NB*NPTS*8u;       // pB 256 KB -> 786688
  const size_t PART_OFF = AABB_OFF + (size_t)NB*NGRP*6*2u;   // ab 12 KB -> 798976
  const size_t CTR_OFF  = PART_OFF + (size_t)NBLK*3*4u;      // 823552
  const size_t NEED     = CTR_OFF + (size_t)NCTR*CSTRIDE*4u; // 831744

  if (ws_size < NEED){
    hipLaunchKernelGGL(init_ws_k, dim3(1), dim3(64), 0, stream, acc);
    hipLaunchKernelGGL(fb_loss_k, dim3((NB*NPTS)/FRPB), dim3(256), 0, stream,
                       pc, fl, gt, acc);
    hipLaunchKernelGGL(fin_k, dim3(1), dim3(1), 0, stream, acc, out);
    return;
  }
  float4* pA = (float4*)(w+SORT_OFF);
  float2* pB = (float2*)(w+PB_OFF);
  unsigned short* ab = (unsigned short*)(w+AABB_OFF);
  float* part = (float*)(w+PART_OFF);
  u32* ctr = (u32*)(w+CTR_OFF);

  hipLaunchKernelGGL(sort_k, dim3(NB),   dim3(1024), 0, stream, pc, fl, pA, pB, ab, ctr);
  hipLaunchKernelGGL(main_k, dim3(NBLK), dim3(256),  0, stream,
                     fl, gt, pA, pB, ab, part, ctr);
  hipLaunchKernelGGL(finp_k, dim3(1), dim3(64), 0, stream, part, out);
}